// Round 5
// baseline (216.125 us; speedup 1.0000x reference)
//
#include <hip/hip_runtime.h>
#include <hip/hip_bf16.h>
#include <cmath>

// Problem constants (from reference)
#define BATCH   2
#define NQ      5376
#define NV      5376
#define CDIM    256
#define HEADS   8
#define HD      32
#define LEVELS  3
#define POINTS  4
#define TP      96      // HEADS*LEVELS*POINTS
#define MROWS   (BATCH*NQ)   // 10752
#define NOFF    (TP*2)       // 192
#define NQA     (NOFF+TP)    // 288 merged off||a columns
#define NQAP    320          // padded rows of merged qa weight (zeros 288..319)

typedef __attribute__((ext_vector_type(8))) short bf16x8;
typedef __attribute__((ext_vector_type(4))) float f32x4;
typedef unsigned short u16;
typedef unsigned int   u32;

#define AS1 __attribute__((address_space(1)))
#define AS3 __attribute__((address_space(3)))

__device__ __forceinline__ void g2lds16(const void* g, void* l) {
    // async global->LDS, 16B per lane; LDS dest = wave-uniform base + lane*16
    __builtin_amdgcn_global_load_lds((const AS1 void*)g, (AS3 void*)l, 16, 0, 0);
}

__device__ __forceinline__ u16 bf_of(float f) {
    union { __hip_bfloat16 h; u16 s; } u;
    u.h = __float2bfloat16(f);
    return u.s;
}
__device__ __forceinline__ float bf_back(u16 s) {
    return __uint_as_float((u32)s << 16);
}

__device__ __forceinline__ ushort4 cvt_hi(float4 v) {
    ushort4 h;
    h.x = bf_of(v.x); h.y = bf_of(v.y); h.z = bf_of(v.z); h.w = bf_of(v.w);
    return h;
}
__device__ __forceinline__ ushort4 cvt_lo(float4 v, ushort4 h) {
    ushort4 l;
    l.x = bf_of(v.x - bf_back(h.x));
    l.y = bf_of(v.y - bf_back(h.y));
    l.z = bf_of(v.z - bf_back(h.z));
    l.w = bf_of(v.w - bf_back(h.w));
    return l;
}

// ---------------------------------------------------------------------------
// Device-scope grid barrier (co-residency guaranteed by the host-side
// occupancy-query grid sizing). Proven correct in round 3 (passed, absmax
// unchanged); round-3 slowness was VGPR spill from launch_bounds, not this.
// ---------------------------------------------------------------------------
__device__ __forceinline__ void grid_barrier(unsigned* bar, int nb) {
    __syncthreads();
    if (threadIdx.x == 0) {
        __builtin_amdgcn_fence(__ATOMIC_RELEASE, "agent");   // L2 writeback
        atomicAdd(bar, 1u);
        while (__hip_atomic_load(bar, __ATOMIC_RELAXED,
                                 __HIP_MEMORY_SCOPE_AGENT) < (unsigned)nb)
            __builtin_amdgcn_s_sleep(2);
        __builtin_amdgcn_fence(__ATOMIC_ACQUIRE, "agent");   // L2 invalidate
    }
    __syncthreads();
}

// ---------------------------------------------------------------------------
// Phase 0: one-shot conversion pass (~40 MB). No `return`s (runs fused).
// ---------------------------------------------------------------------------
#define NVAL8  344064   // 2*5376*256/8
#define NQRY8  344064
#define NWV8   8192     // 256*256/8
#define NWOFF8 6144     // 192*256/8
#define NWA8   3072     // 96*256/8
#define NWO8   8192
#define NPAD8  1024     // 32*256/8
#define PREP_ITEMS (NVAL8+NQRY8+NWV8+NWOFF8+NWA8+NWO8+NPAD8)  // 714752
#define PREP_BLOCKS (PREP_ITEMS/256)   // 2792

__device__ __forceinline__ void prep_item(int r,
    const float* __restrict__ value, const float* __restrict__ query,
    const float* __restrict__ Wv, const float* __restrict__ Woff,
    const float* __restrict__ Wa, const float* __restrict__ Wo,
    u16* __restrict__ val_hi, u16* __restrict__ val_lo,
    u16* __restrict__ q_hi, u16* __restrict__ wv_h,
    u16* __restrict__ wqa_h, u16* __restrict__ wo_h)
{
    if (r < NVAL8) {
        const float4 a0 = *reinterpret_cast<const float4*>(value + (size_t)r * 8);
        const float4 a1 = *reinterpret_cast<const float4*>(value + (size_t)r * 8 + 4);
        const ushort4 h0 = cvt_hi(a0), h1 = cvt_hi(a1);
        *reinterpret_cast<ushort4*>(val_hi + (size_t)r * 8)     = h0;
        *reinterpret_cast<ushort4*>(val_hi + (size_t)r * 8 + 4) = h1;
        *reinterpret_cast<ushort4*>(val_lo + (size_t)r * 8)     = cvt_lo(a0, h0);
        *reinterpret_cast<ushort4*>(val_lo + (size_t)r * 8 + 4) = cvt_lo(a1, h1);
    } else {
        r -= NVAL8;
        if (r < NQRY8) {
            const float4 a0 = *reinterpret_cast<const float4*>(query + (size_t)r * 8);
            const float4 a1 = *reinterpret_cast<const float4*>(query + (size_t)r * 8 + 4);
            *reinterpret_cast<ushort4*>(q_hi + (size_t)r * 8)     = cvt_hi(a0);
            *reinterpret_cast<ushort4*>(q_hi + (size_t)r * 8 + 4) = cvt_hi(a1);
        } else {
            r -= NQRY8;
            if (r < NWV8) {
                const float4 a0 = *reinterpret_cast<const float4*>(Wv + (size_t)r * 8);
                const float4 a1 = *reinterpret_cast<const float4*>(Wv + (size_t)r * 8 + 4);
                *reinterpret_cast<ushort4*>(wv_h + (size_t)r * 8)     = cvt_hi(a0);
                *reinterpret_cast<ushort4*>(wv_h + (size_t)r * 8 + 4) = cvt_hi(a1);
            } else {
                r -= NWV8;
                if (r < NWOFF8) {
                    const float4 a0 = *reinterpret_cast<const float4*>(Woff + (size_t)r * 8);
                    const float4 a1 = *reinterpret_cast<const float4*>(Woff + (size_t)r * 8 + 4);
                    *reinterpret_cast<ushort4*>(wqa_h + (size_t)r * 8)     = cvt_hi(a0);
                    *reinterpret_cast<ushort4*>(wqa_h + (size_t)r * 8 + 4) = cvt_hi(a1);
                } else {
                    r -= NWOFF8;
                    if (r < NWA8) {
                        const float4 a0 = *reinterpret_cast<const float4*>(Wa + (size_t)r * 8);
                        const float4 a1 = *reinterpret_cast<const float4*>(Wa + (size_t)r * 8 + 4);
                        u16* dst = wqa_h + (size_t)NOFF * CDIM;
                        *reinterpret_cast<ushort4*>(dst + (size_t)r * 8)     = cvt_hi(a0);
                        *reinterpret_cast<ushort4*>(dst + (size_t)r * 8 + 4) = cvt_hi(a1);
                    } else {
                        r -= NWA8;
                        if (r < NWO8) {
                            const float4 a0 = *reinterpret_cast<const float4*>(Wo + (size_t)r * 8);
                            const float4 a1 = *reinterpret_cast<const float4*>(Wo + (size_t)r * 8 + 4);
                            *reinterpret_cast<ushort4*>(wo_h + (size_t)r * 8)     = cvt_hi(a0);
                            *reinterpret_cast<ushort4*>(wo_h + (size_t)r * 8 + 4) = cvt_hi(a1);
                        } else {
                            r -= NWO8;
                            const ushort4 z = {0, 0, 0, 0};
                            u16* dst = wqa_h + (size_t)NQA * CDIM;
                            *reinterpret_cast<ushort4*>(dst + (size_t)r * 8)     = z;
                            *reinterpret_cast<ushort4*>(dst + (size_t)r * 8 + 4) = z;
                        }
                    }
                }
            }
        }
    }
}

__device__ __forceinline__ void phase_prep(int bid, int nb,
    const float* value, const float* query, const float* Wv,
    const float* Woff, const float* Wa, const float* Wo,
    u16* val_hi, u16* val_lo, u16* q_hi,
    u16* wv_h, u16* wqa_h, u16* wo_h)
{
    for (int r = bid * 256 + (int)threadIdx.x; r < PREP_ITEMS; r += nb * 256)
        prep_item(r, value, query, Wv, Woff, Wa, Wo,
                  val_hi, val_lo, q_hi, wv_h, wqa_h, wo_h);
}

// ---------------------------------------------------------------------------
// Phase 1: v-GEMM (hi+lo) + qa-GEMM, 64x64x32 tiles, pure bf16, g2lds,
// 2-phase dbuf, chunk-XOR LDS swizzle (rule 21: pre-swizzled global source,
// linear LDS dest, XOR'd read slot).
// ---------------------------------------------------------------------------
#define GBM 64
#define GBN 64
#define GBK 32
#define VBLOCKS (168 * 4)               // 672 v-path tiles
#define K1_BLOCKS (VBLOCKS + 168 * 5)   // 1512

__device__ __forceinline__ void phase_vqa(char* smem, int bid, int nb,
    const u16* __restrict__ val_hi, const u16* __restrict__ val_lo,
    const u16* __restrict__ q_hi,
    const u16* __restrict__ wv_h, const u16* __restrict__ wqa_h,
    const float* __restrict__ bv, const float* __restrict__ boff,
    const float* __restrict__ ba,
    u16* __restrict__ vOut, u16* __restrict__ offOut, u16* __restrict__ aOut)
{
    u16 (*sAh)[GBM * GBK] = reinterpret_cast<u16(*)[GBM * GBK]>(smem);
    u16 (*sAl)[GBM * GBK] = reinterpret_cast<u16(*)[GBM * GBK]>(smem + 8192);
    u16 (*sBh)[GBM * GBK] = reinterpret_cast<u16(*)[GBM * GBK]>(smem + 16384);

    const int tid  = threadIdx.x;
    const int lane = tid & 63;
    const int wave = tid >> 6;
    const int wr   = wave & 1;
    const int wc   = wave >> 1;
    const int qm   = lane & 15;
    const int quad = lane >> 4;
    const int arow = (wave << 4) + (lane >> 2);
    const int ak   = (((lane & 3) ^ ((lane >> 2) & 3)) * 8);  // swizzled src chunk

    for (int t = bid; t < K1_BLOCKS; t += nb) {
        const bool vpath = t < VBLOCKS;
        int m0, n0;
        if (vpath) { m0 = (t >> 2) * GBM;           n0 = (t & 3) * GBM; }
        else       { const int b2 = t - VBLOCKS;
                     m0 = (b2 / 5) * GBM;           n0 = (b2 % 5) * GBM; }

        const u16* Asrc_h = (vpath ? val_hi : q_hi) + (size_t)(m0 + arow) * CDIM + ak;
        const u16* Asrc_l = val_lo + (size_t)(m0 + arow) * CDIM + ak;   // vpath only
        const u16* Bsrc   = (vpath ? wv_h : wqa_h) + (size_t)(n0 + arow) * CDIM + ak;

        f32x4 acc[2][2];
        #pragma unroll
        for (int i = 0; i < 2; ++i)
            #pragma unroll
            for (int j = 0; j < 2; ++j)
                acc[i][j] = (f32x4){0.f, 0.f, 0.f, 0.f};

        g2lds16(Asrc_h, &sAh[0][wave * 512]);
        if (vpath) g2lds16(Asrc_l, &sAl[0][wave * 512]);
        g2lds16(Bsrc, &sBh[0][wave * 512]);
        __syncthreads();

        int cur = 0;
        for (int k0 = 0; k0 < CDIM; k0 += GBK) {
            if (k0 + GBK < CDIM) {
                g2lds16(Asrc_h + k0 + GBK, &sAh[cur ^ 1][wave * 512]);
                if (vpath) g2lds16(Asrc_l + k0 + GBK, &sAl[cur ^ 1][wave * 512]);
                g2lds16(Bsrc + k0 + GBK, &sBh[cur ^ 1][wave * 512]);
            }

            bf16x8 fah[2], fal[2], fbh[2];
            #pragma unroll
            for (int x = 0; x < 2; ++x) {
                const int rm = wr * 32 + x * 16 + qm;
                const int rn = wc * 32 + x * 16 + qm;
                const int ca = (quad ^ (rm & 3)) * 8;
                const int cb = (quad ^ (rn & 3)) * 8;
                fah[x] = *reinterpret_cast<const bf16x8*>(&sAh[cur][rm * GBK + ca]);
                fbh[x] = *reinterpret_cast<const bf16x8*>(&sBh[cur][rn * GBK + cb]);
                if (vpath)
                    fal[x] = *reinterpret_cast<const bf16x8*>(&sAl[cur][rm * GBK + ca]);
            }
            #pragma unroll
            for (int mi = 0; mi < 2; ++mi)
                #pragma unroll
                for (int ni = 0; ni < 2; ++ni) {
                    acc[mi][ni] = __builtin_amdgcn_mfma_f32_16x16x32_bf16(
                        fah[mi], fbh[ni], acc[mi][ni], 0, 0, 0);
                    if (vpath)
                        acc[mi][ni] = __builtin_amdgcn_mfma_f32_16x16x32_bf16(
                            fal[mi], fbh[ni], acc[mi][ni], 0, 0, 0);
                }
            __syncthreads();
            cur ^= 1;
        }

        #pragma unroll
        for (int mi = 0; mi < 2; ++mi) {
            #pragma unroll
            for (int ni = 0; ni < 2; ++ni) {
                const int n = n0 + wc * 32 + ni * 16 + qm;
                if (vpath) {
                    const float bn = bv[n];
                    #pragma unroll
                    for (int r = 0; r < 4; ++r) {
                        const int m = m0 + wr * 32 + mi * 16 + quad * 4 + r;
                        const float val = acc[mi][ni][r] + bn;
                        const int b = m / NV, rr = m - b * NV;
                        const int h = n >> 5, c = n & 31;
                        vOut[(((size_t)b * HEADS + h) * NV + rr) * HD + c] = bf_of(val);
                    }
                } else {
                    if (n < NQA) {
                        const float bn = (n < NOFF) ? boff[n] : ba[n - NOFF];
                        #pragma unroll
                        for (int r = 0; r < 4; ++r) {
                            const int m = m0 + wr * 32 + mi * 16 + quad * 4 + r;
                            const float val = acc[mi][ni][r] + bn;
                            if (n < NOFF)
                                offOut[(size_t)m * NOFF + n] = bf_of(val);
                            else
                                aOut[(size_t)m * TP + (n - NOFF)] = bf_of(val);
                        }
                    }
                }
            }
        }
    }
}

// ---------------------------------------------------------------------------
// Phase 2: MSDA core, WAVE-AUTONOMOUS redesign. Each wave owns one query:
// zero __syncthreads (wave-private LDS slab, in-wave lgkmcnt ordering only),
// softmax exp data-parallel across 64 lanes (was 12-exp serial on 8 threads),
// 1/sum folded into one end-scale of the accumulator (same math, ~1ulp fp32
// reassociation, far below bf16 quantization).
// Slab: s_w[96] @0 | s_mx[8] @384 | s_inv[8] @416 | s_idx[96][4] @448 |
//       s_twt[96][4] @1984 ; total 3520, padded 3584. x4 waves = 14336 B.
// ---------------------------------------------------------------------------
#define MSDA_SLAB 3584

__device__ __forceinline__ void phase_msda(char* smem, int bid, int nb,
    const u16* __restrict__ off, const u16* __restrict__ alog,
    const float* __restrict__ refp, const u16* __restrict__ v,
    u16* __restrict__ t_hi)
{
    const int tid  = threadIdx.x;
    const int wave = tid >> 6;
    const int lane = tid & 63;

    char* slab = smem + wave * MSDA_SLAB;
    float* s_w   = reinterpret_cast<float*>(slab);
    float* s_mx  = reinterpret_cast<float*>(slab + 384);
    float* s_inv = reinterpret_cast<float*>(slab + 416);
    int*   s_idx = reinterpret_cast<int*>  (slab + 448);
    float* s_twt = reinterpret_cast<float*>(slab + 1984);

    // gather mapping (fixed per lane)
    const int h   = lane >> 3;
    const int sub = lane & 7;
    const int oct = sub & 3;
    const int rep = sub >> 2;

    for (int g0 = bid; g0 < MROWS / 4; g0 += nb) {
        const int bq = g0 * 4 + wave;
        const int b  = bq / NQ;

        // --- A: logits (12 lanes x 8 bf16 -> f32 in LDS) ---
        if (lane < 12) {
            const bf16x8 lg = *reinterpret_cast<const bf16x8*>(
                &alog[(size_t)bq * TP + lane * 8]);
            float4 f0, f1;
            f0.x = bf_back((u16)lg[0]); f0.y = bf_back((u16)lg[1]);
            f0.z = bf_back((u16)lg[2]); f0.w = bf_back((u16)lg[3]);
            f1.x = bf_back((u16)lg[4]); f1.y = bf_back((u16)lg[5]);
            f1.z = bf_back((u16)lg[6]); f1.w = bf_back((u16)lg[7]);
            *reinterpret_cast<float4*>(&s_w[lane * 8])     = f0;
            *reinterpret_cast<float4*>(&s_w[lane * 8 + 4]) = f1;
        }

        // --- B: per-head max (8 lanes, 12-wide) ---
        if (lane < 8) {
            const float4 a = *reinterpret_cast<const float4*>(&s_w[lane * 12]);
            const float4 c = *reinterpret_cast<const float4*>(&s_w[lane * 12 + 4]);
            const float4 d = *reinterpret_cast<const float4*>(&s_w[lane * 12 + 8]);
            const float mx = fmaxf(
                fmaxf(fmaxf(a.x, a.y), fmaxf(a.z, a.w)),
                fmaxf(fmaxf(fmaxf(c.x, c.y), fmaxf(c.z, c.w)),
                      fmaxf(fmaxf(d.x, d.y), fmaxf(d.z, d.w))));
            s_mx[lane] = mx;
        }

        // --- C: taps, data-parallel (tap j=lane; lanes<32 also j=64+lane) ---
        const float refx = refp[(size_t)bq * 2 + 0];
        const float refy = refp[(size_t)bq * 2 + 1];
        #pragma unroll
        for (int half = 0; half < 2; ++half) {
            const int j = half * 64 + lane;
            if (half == 0 || lane < 32) {
                const int jj = j % 12;
                const int l  = jj >> 2;
                const int Wl    = (l == 0) ? 64 : (l == 1) ? 32 : 16;
                const int start = (l == 0) ? 0 : (l == 1) ? 4096 : 5120;

                const u32 o2 = *reinterpret_cast<const u32*>(
                    &off[(size_t)bq * NOFF + j * 2]);
                const float ox = bf_back((u16)(o2 & 0xffffu));
                const float oy = bf_back((u16)(o2 >> 16));
                const float lw  = s_w[j];
                const float mxh = s_mx[j / 12];
                const float aw  = expf(lw - mxh);   // unnormalized

                const float lx = fminf(fmaxf(refx + ox, 0.f), 1.f) * (float)Wl - 0.5f;
                const float ly = fminf(fmaxf(refy + oy, 0.f), 1.f) * (float)Wl - 0.5f;
                const float fx0 = floorf(lx), fy0 = floorf(ly);
                const int   x0  = (int)fx0,   y0  = (int)fy0;
                const float wx1 = lx - fx0,   wy1 = ly - fy0;
                const float wx0 = 1.f - wx1,  wy0 = 1.f - wy1;

                int   idv[4];
                float twv[4];
                #pragma unroll
                for (int k = 0; k < 4; ++k) {
                    const int dx = k & 1, dy = k >> 1;
                    const int xi = x0 + dx, yi = y0 + dy;
                    const bool ok = (xi >= 0) & (xi < Wl) & (yi >= 0) & (yi < Wl);
                    const int xc = min(max(xi, 0), Wl - 1);
                    const int yc = min(max(yi, 0), Wl - 1);
                    idv[k] = (start + yc * Wl + xc) * (HD * 2);   // 64 B rows
                    const float wxy = (dx ? wx1 : wx0) * (dy ? wy1 : wy0);
                    twv[k] = ok ? aw * wxy : 0.f;
                }
                int4 id; id.x = idv[0]; id.y = idv[1]; id.z = idv[2]; id.w = idv[3];
                float4 tw; tw.x = twv[0]; tw.y = twv[1]; tw.z = twv[2]; tw.w = twv[3];
                *reinterpret_cast<int4*>(&s_idx[j * 4])   = id;
                *reinterpret_cast<float4*>(&s_twt[j * 4]) = tw;
                s_w[j] = aw;   // for the sum
            }
        }

        // --- D: per-head 1/sum (8 lanes) ---
        if (lane < 8) {
            const float4 a = *reinterpret_cast<const float4*>(&s_w[lane * 12]);
            const float4 c = *reinterpret_cast<const float4*>(&s_w[lane * 12 + 4]);
            const float4 d = *reinterpret_cast<const float4*>(&s_w[lane * 12 + 8]);
            const float sum = ((a.x + a.y) + (a.z + a.w))
                            + ((c.x + c.y) + (c.z + c.w))
                            + ((d.x + d.y) + (d.z + d.w));
            s_inv[lane] = 1.f / sum;
        }

        // --- E: gather (identical structure, per-wave slab) ---
        const char* vb = (const char*)v
            + (((size_t)b * HEADS + h) * NV) * (HD * 2) + oct * 16;

        float acc[8] = {};
        #pragma unroll
        for (int g = 0; g < 3; ++g) {
            uint4 raw[8];
            float wt[8];
            #pragma unroll
            for (int pp = 0; pp < 2; ++pp) {
                const int j = h * 12 + rep * 6 + g * 2 + pp;
                const int4   ix = *reinterpret_cast<const int4*>(&s_idx[j * 4]);
                const float4 tw = *reinterpret_cast<const float4*>(&s_twt[j * 4]);
                raw[pp * 4 + 0] = *reinterpret_cast<const uint4*>(vb + ix.x);
                raw[pp * 4 + 1] = *reinterpret_cast<const uint4*>(vb + ix.y);
                raw[pp * 4 + 2] = *reinterpret_cast<const uint4*>(vb + ix.z);
                raw[pp * 4 + 3] = *reinterpret_cast<const uint4*>(vb + ix.w);
                wt[pp * 4 + 0] = tw.x; wt[pp * 4 + 1] = tw.y;
                wt[pp * 4 + 2] = tw.z; wt[pp * 4 + 3] = tw.w;
            }
            #pragma unroll
            for (int k = 0; k < 8; ++k) {
                acc[0] += wt[k] * __uint_as_float(raw[k].x << 16);
                acc[1] += wt[k] * __uint_as_float(raw[k].x & 0xffff0000u);
                acc[2] += wt[k] * __uint_as_float(raw[k].y << 16);
                acc[3] += wt[k] * __uint_as_float(raw[k].y & 0xffff0000u);
                acc[4] += wt[k] * __uint_as_float(raw[k].z << 16);
                acc[5] += wt[k] * __uint_as_float(raw[k].z & 0xffff0000u);
                acc[6] += wt[k] * __uint_as_float(raw[k].w << 16);
                acc[7] += wt[k] * __uint_as_float(raw[k].w & 0xffff0000u);
            }
        }

        const float inv = s_inv[h];
        #pragma unroll
        for (int c = 0; c < 8; ++c)
            acc[c] = (acc[c] + __shfl_xor(acc[c], 4)) * inv;

        if (rep == 0) {
            uint4 o;
            o.x = (u32)bf_of(acc[0]) | ((u32)bf_of(acc[1]) << 16);
            o.y = (u32)bf_of(acc[2]) | ((u32)bf_of(acc[3]) << 16);
            o.z = (u32)bf_of(acc[4]) | ((u32)bf_of(acc[5]) << 16);
            o.w = (u32)bf_of(acc[6]) | ((u32)bf_of(acc[7]) << 16);
            const size_t base = (size_t)bq * CDIM + h * HD + oct * 8;
            *reinterpret_cast<uint4*>(t_hi + base) = o;
        }
    }
}

// ---------------------------------------------------------------------------
// Phase 3: out = t @ Wo^T + bo (fp32 out), same swizzled structure.
// ---------------------------------------------------------------------------
#define K3_BLOCKS ((MROWS / GBM) * 4)   // 672

__device__ __forceinline__ void phase_out(char* smem, int bid, int nb,
    const u16* __restrict__ Ah, const u16* __restrict__ wo_h,
    const float* __restrict__ bias, float* __restrict__ Cout)
{
    u16 (*sAh)[GBM * GBK] = reinterpret_cast<u16(*)[GBM * GBK]>(smem);
    u16 (*sBh)[GBM * GBK] = reinterpret_cast<u16(*)[GBM * GBK]>(smem + 8192);

    const int tid  = threadIdx.x;
    const int lane = tid & 63;
    const int wave = tid >> 6;
    const int wr   = wave & 1;
    const int wc   = wave >> 1;
    const int qm   = lane & 15;
    const int quad = lane >> 4;
    const int arow = (wave << 4) + (lane >> 2);
    const int ak   = (((lane & 3) ^ ((lane >> 2) & 3)) * 8);

    for (int t = bid; t < K3_BLOCKS; t += nb) {
        const int m0 = (t >> 2) * GBM;
        const int n0 = (t & 3) * GBN;

        const u16* Asrc = Ah   + (size_t)(m0 + arow) * CDIM + ak;
        const u16* Bsrc = wo_h + (size_t)(n0 + arow) * CDIM + ak;

        f32x4 acc[2][2];
        #pragma unroll
        for (int i = 0; i < 2; ++i)
            #pragma unroll
            for (int j = 0; j < 2; ++j)
                acc[i][j] = (f32x4){0.f, 0.f, 0.f, 0.f};

        g2lds16(Asrc, &sAh[0][wave * 512]);
        g2lds16(Bsrc, &sBh[0][wave * 512]);
        __syncthreads();

        int cur = 0;
        for (int k0 = 0; k0 < CDIM; k0 += GBK) {
            if (k0 + GBK < CDIM) {
                g2lds16(Asrc + k0 + GBK, &sAh[cur ^ 1][wave * 512]);
                g2lds16(Bsrc + k0 + GBK, &sBh[cur ^ 1][wave * 512]);
            }

            bf16x8 fah[2], fbh[2];
            #pragma unroll
            for (int x = 0; x < 2; ++x) {
                const int rm = wr * 32 + x * 16 + qm;
                const int rn = wc * 32 + x * 16 + qm;
                const int ca = (quad ^ (rm & 3)) * 8;
                const int cb = (quad ^ (rn & 3)) * 8;
                fah[x] = *reinterpret_cast<const bf16x8*>(&sAh[cur][rm * GBK + ca]);
                fbh[x] = *reinterpret_cast<const bf16x8*>(&sBh[cur][rn * GBK + cb]);
            }
            #pragma unroll
            for (int mi = 0; mi < 2; ++mi)
                #pragma unroll
                for (int ni = 0; ni < 2; ++ni)
                    acc[mi][ni] = __builtin_amdgcn_mfma_f32_16x16x32_bf16(
                        fah[mi], fbh[ni], acc[mi][ni], 0, 0, 0);
            __syncthreads();
            cur ^= 1;
        }

        #pragma unroll
        for (int mi = 0; mi < 2; ++mi) {
            #pragma unroll
            for (int ni = 0; ni < 2; ++ni) {
                const int n = n0 + wc * 32 + ni * 16 + qm;
                const float bn = bias[n];
                #pragma unroll
                for (int r = 0; r < 4; ++r) {
                    const int m = m0 + wr * 32 + mi * 16 + quad * 4 + r;
                    Cout[(size_t)m * CDIM + n] = acc[mi][ni][r] + bn;
                }
            }
        }
    }
}

// ---------------------------------------------------------------------------
// Fused single-dispatch kernel. NO min-occupancy launch bound — round 3's
// 395us was VGPR spill from __launch_bounds__(256,4) (VGPR_Count=64 vs ~110
// needed; excess 80MB HBM traffic = scratch). Grid is sized from the real
// occupancy query, so co-residency still holds.
// ---------------------------------------------------------------------------
__global__ __launch_bounds__(256) void fused_all(
    const float* __restrict__ value, const float* __restrict__ query,
    const float* __restrict__ Wv, const float* __restrict__ Woff,
    const float* __restrict__ Wa, const float* __restrict__ Wo,
    const float* __restrict__ bv, const float* __restrict__ boff,
    const float* __restrict__ ba, const float* __restrict__ bo,
    const float* __restrict__ refp,
    u16* val_hi, u16* val_lo, u16* q_hi,
    u16* wv_h, u16* wqa_h, u16* wo_h,
    u16* v_bf16, u16* ws_off, u16* ws_a, u16* t_hi,
    float* out, unsigned* bars)
{
    __shared__ __align__(16) char smem[24576];
    const int bid = blockIdx.x;
    const int nb  = gridDim.x;

    phase_prep(bid, nb, value, query, Wv, Woff, Wa, Wo,
               val_hi, val_lo, q_hi, wv_h, wqa_h, wo_h);
    grid_barrier(bars + 0, nb);

    phase_vqa(smem, bid, nb, val_hi, val_lo, q_hi, wv_h, wqa_h,
              bv, boff, ba, v_bf16, ws_off, ws_a);
    grid_barrier(bars + 32, nb);

    phase_msda(smem, bid, nb, ws_off, ws_a, refp, v_bf16, t_hi);
    grid_barrier(bars + 64, nb);

    phase_out(smem, bid, nb, t_hi, wo_h, bo, out);
}

// ---------------------------------------------------------------------------
// Fallback thin kernels (used only if the occupancy query fails).
// ---------------------------------------------------------------------------
__global__ __launch_bounds__(256) void prep_k(
    const float* value, const float* query, const float* Wv,
    const float* Woff, const float* Wa, const float* Wo,
    u16* val_hi, u16* val_lo, u16* q_hi, u16* wv_h, u16* wqa_h, u16* wo_h)
{
    phase_prep(blockIdx.x, gridDim.x, value, query, Wv, Woff, Wa, Wo,
               val_hi, val_lo, q_hi, wv_h, wqa_h, wo_h);
}

__global__ __launch_bounds__(256) void vqa_k(
    const u16* val_hi, const u16* val_lo, const u16* q_hi,
    const u16* wv_h, const u16* wqa_h,
    const float* bv, const float* boff, const float* ba,
    u16* vOut, u16* offOut, u16* aOut)
{
    __shared__ __align__(16) char smem[24576];
    phase_vqa(smem, blockIdx.x, gridDim.x, val_hi, val_lo, q_hi, wv_h, wqa_h,
              bv, boff, ba, vOut, offOut, aOut);
}

__global__ __launch_bounds__(256) void msda_k(
    const u16* off, const u16* alog, const float* refp, const u16* v, u16* t_hi)
{
    __shared__ __align__(16) char smem[4 * MSDA_SLAB];
    phase_msda(smem, blockIdx.x, gridDim.x, off, alog, refp, v, t_hi);
}

__global__ __launch_bounds__(256) void out_k(
    const u16* Ah, const u16* wo_h, const float* bias, float* Cout)
{
    __shared__ __align__(16) char smem[16384];
    phase_out(smem, blockIdx.x, gridDim.x, Ah, wo_h, bias, Cout);
}

// ---------------------------------------------------------------------------
// Launch: 1 memset node + 1 fused dispatch (fallback: 4 dispatches).
// ---------------------------------------------------------------------------
extern "C" void kernel_launch(void* const* d_in, const int* in_sizes, int n_in,
                              void* d_out, int out_size, void* d_ws, size_t ws_size,
                              hipStream_t stream)
{
    const float* query = (const float*)d_in[0];   // (B,NQ,C)
    const float* refp  = (const float*)d_in[1];   // (B,NQ,2)
    const float* value = (const float*)d_in[2];   // (B,NV,C)
    const float* Wv    = (const float*)d_in[3];   // (C,C)
    const float* bv    = (const float*)d_in[4];
    const float* Woff  = (const float*)d_in[5];   // (192,C)
    const float* boff  = (const float*)d_in[6];
    const float* Wa    = (const float*)d_in[7];   // (96,C)
    const float* ba    = (const float*)d_in[8];
    const float* Wo    = (const float*)d_in[9];   // (C,C)
    const float* bo    = (const float*)d_in[10];
    float* out = (float*)d_out;

    // ---- workspace layout ----
    char* w = (char*)d_ws;
    const size_t SZ_T = (size_t)MROWS * CDIM * 2;     // 5.5 MB
    u16* v_bf16 = (u16*)(w);
    u16* t_hi   = (u16*)(w + 1 * SZ_T);
    u16* ws_off = (u16*)(w + 2 * SZ_T);               // (MROWS,192) bf16
    u16* ws_a   = (u16*)(w + 2 * SZ_T + (size_t)MROWS * NOFF * 2);
    char* w2    = w + 2 * SZ_T + (size_t)MROWS * NQA * 2;
    u16* val_hi = (u16*)(w2);
    u16* val_lo = (u16*)(w2 + 1 * SZ_T);
    u16* q_hi   = (u16*)(w2 + 2 * SZ_T);
    u16* wv_h   = (u16*)(w2 + 3 * SZ_T);
    u16* wqa_h  = (u16*)(w2 + 3 * SZ_T + (size_t)CDIM * CDIM * 2);
    u16* wo_h   = (u16*)(w2 + 3 * SZ_T + (size_t)CDIM * CDIM * 2
                              + (size_t)NQAP * CDIM * 2);
    unsigned* bars = (unsigned*)(w2 + 3 * SZ_T + (size_t)CDIM * CDIM * 2
                              + (size_t)NQAP * CDIM * 2
                              + (size_t)CDIM * CDIM * 2);

    const dim3 blk(256);

    int mb = 0;
    hipError_t qe = hipOccupancyMaxActiveBlocksPerMultiprocessor(&mb, fused_all, 256, 0);

    if (qe == hipSuccess && mb >= 1) {
        const int grid = mb * 256;   // guaranteed co-resident on 256 CUs
        hipMemsetAsync(bars, 0, 512, stream);   // zero barrier counters each replay
        fused_all<<<dim3(grid), blk, 0, stream>>>(
            value, query, Wv, Woff, Wa, Wo, bv, boff, ba, bo, refp,
            val_hi, val_lo, q_hi, wv_h, wqa_h, wo_h,
            v_bf16, ws_off, ws_a, t_hi, out, bars);
    } else {
        // fallback: proven 4-dispatch pipeline
        prep_k<<<dim3(PREP_BLOCKS), blk, 0, stream>>>(
            value, query, Wv, Woff, Wa, Wo,
            val_hi, val_lo, q_hi, wv_h, wqa_h, wo_h);
        vqa_k<<<dim3(K1_BLOCKS), blk, 0, stream>>>(
            val_hi, val_lo, q_hi, wv_h, wqa_h, bv, boff, ba,
            v_bf16, ws_off, ws_a);
        msda_k<<<dim3(MROWS / 4), blk, 0, stream>>>(
            ws_off, ws_a, refp, v_bf16, t_hi);
        out_k<<<dim3(K3_BLOCKS), blk, 0, stream>>>(
            t_hi, wo_h, bo, out);
    }
}

// Round 6
// 131.460 us; speedup vs baseline: 1.6440x; 1.6440x over previous
//
#include <hip/hip_runtime.h>
#include <hip/hip_bf16.h>
#include <cmath>

// Problem constants
#define BATCH   2
#define NQ      5376
#define NV      5376
#define CDIM    256
#define HEADS   8
#define HD      32
#define LEVELS  3
#define POINTS  4
#define TP      96
#define MROWS   (BATCH*NQ)   // 10752
#define NOFF    (TP*2)       // 192
#define NQA     (NOFF+TP)    // 288

typedef __attribute__((ext_vector_type(8))) short bf16x8;
typedef __attribute__((ext_vector_type(4))) float f32x4;
typedef unsigned short u16;
typedef unsigned int   u32;

__device__ __forceinline__ u16 bf_of(float f) {
    union { __hip_bfloat16 h; u16 s; } u;
    u.h = __float2bfloat16(f);
    return u.s;
}
__device__ __forceinline__ float bf_back(u16 s) {
    return __uint_as_float((u32)s << 16);
}
__device__ __forceinline__ ushort4 cvt_hi(float4 v) {
    ushort4 h;
    h.x = bf_of(v.x); h.y = bf_of(v.y); h.z = bf_of(v.z); h.w = bf_of(v.w);
    return h;
}
__device__ __forceinline__ ushort4 cvt_lo(float4 v, ushort4 h) {
    ushort4 l;
    l.x = bf_of(v.x - bf_back(h.x));
    l.y = bf_of(v.y - bf_back(h.y));
    l.z = bf_of(v.z - bf_back(h.z));
    l.w = bf_of(v.w - bf_back(h.w));
    return l;
}

// ---------------------------------------------------------------------------
// Kernel 1: v-GEMM (hi+lo split) + qa-GEMM with INLINE fp32->bf16 conversion
// during staging (round-0 proven structure), 64x64x32 tiles, 4 waves.
// LDS rows padded to stride 40 u16 (80 B): frag ds_read_b128 goes 8-way ->
// 2-way bank aliasing (free). Side-job: blocks 0..31 also convert Wo -> wo_h
// (consumed by kernel 2 via stream order).
// ---------------------------------------------------------------------------
#define GBM 64
#define GBN 64
#define GBK 32
#define SAP 40                          // padded LDS row stride in u16

#define VBLOCKS (168 * 4)               // 672 v-path blocks
#define K1_BLOCKS (VBLOCKS + 168 * 5)   // 1512, %8==0
#define K1_CPX (K1_BLOCKS / 8)          // 189

__global__ __launch_bounds__(256) void gemm_vqa_conv(
    const float* __restrict__ value, const float* __restrict__ Wv,
    const float* __restrict__ bv, u16* __restrict__ vOut,
    const float* __restrict__ query, const float* __restrict__ Woff,
    const float* __restrict__ Wa,
    const float* __restrict__ boff, const float* __restrict__ ba,
    u16* __restrict__ offOut, u16* __restrict__ aOut,
    const float* __restrict__ Wo, u16* __restrict__ wo_h)
{
    __shared__ __align__(16) u16 sAh[GBM * SAP];   // 5120 B each
    __shared__ __align__(16) u16 sAl[GBM * SAP];
    __shared__ __align__(16) u16 sBh[GBM * SAP];

    const int bid0 = blockIdx.x;
    const int tid  = threadIdx.x;

    // side-job: convert Wo (256x256 fp32) -> wo_h bf16. 32 blocks x 256 thr x 8.
    if (bid0 < 32) {
        const int e = bid0 * 2048 + tid * 8;
        const float4 a0 = *reinterpret_cast<const float4*>(Wo + e);
        const float4 a1 = *reinterpret_cast<const float4*>(Wo + e + 4);
        *reinterpret_cast<ushort4*>(wo_h + e)     = cvt_hi(a0);
        *reinterpret_cast<ushort4*>(wo_h + e + 4) = cvt_hi(a1);
    }

    // XCD-chunk swizzle (1512 % 8 == 0 -> bijective)
    const int bid = (bid0 & 7) * K1_CPX + (bid0 >> 3);

    const bool vpath = bid < VBLOCKS;
    int m0, n0;
    if (vpath) { m0 = (bid >> 2) * GBM;          n0 = (bid & 3) * GBN; }
    else       { const int b2 = bid - VBLOCKS;
                 m0 = (b2 / 5) * GBM;            n0 = (b2 % 5) * GBN; }

    const int lane = tid & 63;
    const int wave = tid >> 6;
    const int wr   = wave & 1;
    const int wc   = wave >> 1;
    const int qm   = lane & 15;
    const int quad = lane >> 4;

    // staging map: row = tid>>2 (0..63), k-offset = (tid&3)*8 floats
    const int srow = tid >> 2;
    const int sc   = (tid & 3) * 8;

    const float* Asrc = (vpath ? value : query) + (size_t)(m0 + srow) * CDIM;
    const float* Bsrc;
    if (vpath) {
        Bsrc = Wv + (size_t)(n0 + srow) * CDIM;
    } else {
        const int rg = min(n0 + srow, NQA - 1);
        Bsrc = (rg < NOFF) ? (Woff + (size_t)rg * CDIM)
                           : (Wa + (size_t)(rg - NOFF) * CDIM);
    }

    f32x4 acc[2][2];
    #pragma unroll
    for (int i = 0; i < 2; ++i)
        #pragma unroll
        for (int j = 0; j < 2; ++j)
            acc[i][j] = (f32x4){0.f, 0.f, 0.f, 0.f};

    for (int k0 = 0; k0 < CDIM; k0 += GBK) {
        // ---- stage A (hi, + lo on v path) with inline conversion ----
        const float4 a0 = *reinterpret_cast<const float4*>(&Asrc[k0 + sc]);
        const float4 a1 = *reinterpret_cast<const float4*>(&Asrc[k0 + sc + 4]);
        const ushort4 ah0 = cvt_hi(a0), ah1 = cvt_hi(a1);
        *reinterpret_cast<ushort4*>(&sAh[srow * SAP + sc])     = ah0;
        *reinterpret_cast<ushort4*>(&sAh[srow * SAP + sc + 4]) = ah1;
        if (vpath) {
            *reinterpret_cast<ushort4*>(&sAl[srow * SAP + sc])     = cvt_lo(a0, ah0);
            *reinterpret_cast<ushort4*>(&sAl[srow * SAP + sc + 4]) = cvt_lo(a1, ah1);
        }
        // ---- stage B (hi only) ----
        const float4 b0 = *reinterpret_cast<const float4*>(&Bsrc[k0 + sc]);
        const float4 b1 = *reinterpret_cast<const float4*>(&Bsrc[k0 + sc + 4]);
        *reinterpret_cast<ushort4*>(&sBh[srow * SAP + sc])     = cvt_hi(b0);
        *reinterpret_cast<ushort4*>(&sBh[srow * SAP + sc + 4]) = cvt_hi(b1);
        __syncthreads();

        bf16x8 fah[2], fal[2], fbh[2];
        #pragma unroll
        for (int x = 0; x < 2; ++x) {
            const int rm = wr * 32 + x * 16 + qm;
            const int rn = wc * 32 + x * 16 + qm;
            fah[x] = *reinterpret_cast<const bf16x8*>(&sAh[rm * SAP + quad * 8]);
            fbh[x] = *reinterpret_cast<const bf16x8*>(&sBh[rn * SAP + quad * 8]);
            if (vpath)
                fal[x] = *reinterpret_cast<const bf16x8*>(&sAl[rm * SAP + quad * 8]);
        }
        #pragma unroll
        for (int mi = 0; mi < 2; ++mi)
            #pragma unroll
            for (int ni = 0; ni < 2; ++ni) {
                acc[mi][ni] = __builtin_amdgcn_mfma_f32_16x16x32_bf16(
                    fah[mi], fbh[ni], acc[mi][ni], 0, 0, 0);
                if (vpath)
                    acc[mi][ni] = __builtin_amdgcn_mfma_f32_16x16x32_bf16(
                        fal[mi], fbh[ni], acc[mi][ni], 0, 0, 0);
            }
        __syncthreads();
    }

    // epilogue: C/D layout col = lane&15 (n), row = quad*4 + reg (m)
    #pragma unroll
    for (int mi = 0; mi < 2; ++mi) {
        #pragma unroll
        for (int ni = 0; ni < 2; ++ni) {
            const int n = n0 + wc * 32 + ni * 16 + qm;
            if (vpath) {
                const float bn = bv[n];
                #pragma unroll
                for (int r = 0; r < 4; ++r) {
                    const int m = m0 + wr * 32 + mi * 16 + quad * 4 + r;
                    const float val = acc[mi][ni][r] + bn;
                    // head-major (B, HEADS, NV, HD)
                    const int b = m / NV, rr = m - b * NV;
                    const int h = n >> 5, c = n & 31;
                    vOut[(((size_t)b * HEADS + h) * NV + rr) * HD + c] = bf_of(val);
                }
            } else {
                if (n >= NQA) continue;
                const float bn = (n < NOFF) ? boff[n] : ba[n - NOFF];
                #pragma unroll
                for (int r = 0; r < 4; ++r) {
                    const int m = m0 + wr * 32 + mi * 16 + quad * 4 + r;
                    const float val = acc[mi][ni][r] + bn;
                    if (n < NOFF)
                        offOut[(size_t)m * NOFF + n] = bf_of(val);
                    else
                        aOut[(size_t)m * TP + (n - NOFF)] = bf_of(val);
                }
            }
        }
    }
}

// ---------------------------------------------------------------------------
// Kernel 2: msda + out-GEMM fused. 672 blocks x 512 threads (8 waves).
// Each block owns 16 consecutive queries:
//   phase A (wave-autonomous msda, round-5-proven numerics): each wave
//     computes 2 queries (iter*8+wave) -> t rows written to LDS (bf16,
//     padded stride 264 u16 -> 2-way bank aliasing on frag reads).
//   one barrier.
//   phase B: out[16 x 256] = t_lds @ Wo^T + bo. A-frags from LDS; B-frags
//     read directly from L2-resident wo_h (128 KB); no staging, no barriers.
// t never touches HBM; k3 dispatch eliminated.
// ---------------------------------------------------------------------------
#define MSDA_SLAB 3584
#define QPB 16
#define K2_BLOCKS (MROWS / QPB)   // 672, %8==0
#define K2_CPX (K2_BLOCKS / 8)    // 84
#define TSTR 264                  // t_lds row stride in u16 (528 B, 16B-mult)

__global__ __launch_bounds__(512) void msda_out_kernel(
    const u16* __restrict__ off,    // (B*NQ, 192) bf16
    const u16* __restrict__ alog,   // (B*NQ, 96) bf16
    const float* __restrict__ refp, // (B*NQ, 2)
    const u16*   __restrict__ v,    // (B, HEADS, NV, HD) bf16
    const u16*   __restrict__ wo_h, // (256, 256) bf16
    const float* __restrict__ bo,
    float* __restrict__ out)        // (B*NQ, 256) fp32
{
    __shared__ __align__(16) char slabs[8 * MSDA_SLAB];   // 28672 B
    __shared__ __align__(16) u16  t_lds[QPB * TSTR];      // 8448 B

    const int tid  = threadIdx.x;
    const int wave = tid >> 6;      // 0..7
    const int lane = tid & 63;

    const int bid0 = blockIdx.x;
    const int bid  = (bid0 & 7) * K2_CPX + (bid0 >> 3);
    const int bq0  = bid * QPB;

    char* slab = slabs + wave * MSDA_SLAB;
    float* s_w   = reinterpret_cast<float*>(slab);
    float* s_mx  = reinterpret_cast<float*>(slab + 384);
    float* s_inv = reinterpret_cast<float*>(slab + 416);
    int*   s_idx = reinterpret_cast<int*>  (slab + 448);
    float* s_twt = reinterpret_cast<float*>(slab + 1984);

    const int h   = lane >> 3;
    const int sub = lane & 7;
    const int oct = sub & 3;
    const int rep = sub >> 2;

    // ---------------- phase A: msda, 2 queries per wave ----------------
    #pragma unroll
    for (int iter = 0; iter < 2; ++iter) {
        const int r  = iter * 8 + wave;     // t row 0..15
        const int bq = bq0 + r;
        const int b  = bq / NQ;

        // logits (12 lanes x 8 bf16 -> f32)
        if (lane < 12) {
            const bf16x8 lg = *reinterpret_cast<const bf16x8*>(
                &alog[(size_t)bq * TP + lane * 8]);
            float4 f0, f1;
            f0.x = bf_back((u16)lg[0]); f0.y = bf_back((u16)lg[1]);
            f0.z = bf_back((u16)lg[2]); f0.w = bf_back((u16)lg[3]);
            f1.x = bf_back((u16)lg[4]); f1.y = bf_back((u16)lg[5]);
            f1.z = bf_back((u16)lg[6]); f1.w = bf_back((u16)lg[7]);
            *reinterpret_cast<float4*>(&s_w[lane * 8])     = f0;
            *reinterpret_cast<float4*>(&s_w[lane * 8 + 4]) = f1;
        }

        // per-head max (8 lanes)
        if (lane < 8) {
            const float4 a = *reinterpret_cast<const float4*>(&s_w[lane * 12]);
            const float4 c = *reinterpret_cast<const float4*>(&s_w[lane * 12 + 4]);
            const float4 d = *reinterpret_cast<const float4*>(&s_w[lane * 12 + 8]);
            s_mx[lane] = fmaxf(
                fmaxf(fmaxf(a.x, a.y), fmaxf(a.z, a.w)),
                fmaxf(fmaxf(fmaxf(c.x, c.y), fmaxf(c.z, c.w)),
                      fmaxf(fmaxf(d.x, d.y), fmaxf(d.z, d.w))));
        }

        // taps, data-parallel (tap j = lane; lanes<32 also j = 64+lane)
        const float refx = refp[(size_t)bq * 2 + 0];
        const float refy = refp[(size_t)bq * 2 + 1];
        #pragma unroll
        for (int half = 0; half < 2; ++half) {
            const int j = half * 64 + lane;
            if (half == 0 || lane < 32) {
                const int jj = j % 12;
                const int l  = jj >> 2;
                const int Wl    = (l == 0) ? 64 : (l == 1) ? 32 : 16;
                const int start = (l == 0) ? 0 : (l == 1) ? 4096 : 5120;

                const u32 o2 = *reinterpret_cast<const u32*>(
                    &off[(size_t)bq * NOFF + j * 2]);
                const float ox = bf_back((u16)(o2 & 0xffffu));
                const float oy = bf_back((u16)(o2 >> 16));
                const float aw = expf(s_w[j] - s_mx[j / 12]);   // unnormalized

                const float lx = fminf(fmaxf(refx + ox, 0.f), 1.f) * (float)Wl - 0.5f;
                const float ly = fminf(fmaxf(refy + oy, 0.f), 1.f) * (float)Wl - 0.5f;
                const float fx0 = floorf(lx), fy0 = floorf(ly);
                const int   x0  = (int)fx0,   y0  = (int)fy0;
                const float wx1 = lx - fx0,   wy1 = ly - fy0;
                const float wx0 = 1.f - wx1,  wy0 = 1.f - wy1;

                int   idv[4];
                float twv[4];
                #pragma unroll
                for (int k = 0; k < 4; ++k) {
                    const int dx = k & 1, dy = k >> 1;
                    const int xi = x0 + dx, yi = y0 + dy;
                    const bool ok = (xi >= 0) & (xi < Wl) & (yi >= 0) & (yi < Wl);
                    const int xc = min(max(xi, 0), Wl - 1);
                    const int yc = min(max(yi, 0), Wl - 1);
                    idv[k] = (start + yc * Wl + xc) * (HD * 2);
                    const float wxy = (dx ? wx1 : wx0) * (dy ? wy1 : wy0);
                    twv[k] = ok ? aw * wxy : 0.f;
                }
                int4 id; id.x = idv[0]; id.y = idv[1]; id.z = idv[2]; id.w = idv[3];
                float4 tw; tw.x = twv[0]; tw.y = twv[1]; tw.z = twv[2]; tw.w = twv[3];
                *reinterpret_cast<int4*>(&s_idx[j * 4])   = id;
                *reinterpret_cast<float4*>(&s_twt[j * 4]) = tw;
                s_w[j] = aw;
            }
        }

        // per-head 1/sum (8 lanes)
        if (lane < 8) {
            const float4 a = *reinterpret_cast<const float4*>(&s_w[lane * 12]);
            const float4 c = *reinterpret_cast<const float4*>(&s_w[lane * 12 + 4]);
            const float4 d = *reinterpret_cast<const float4*>(&s_w[lane * 12 + 8]);
            s_inv[lane] = 1.f / (((a.x + a.y) + (a.z + a.w))
                               + ((c.x + c.y) + (c.z + c.w))
                               + ((d.x + d.y) + (d.z + d.w)));
        }

        // gather
        const char* vb = (const char*)v
            + (((size_t)b * HEADS + h) * NV) * (HD * 2) + oct * 16;

        float acc[8] = {};
        #pragma unroll
        for (int g = 0; g < 3; ++g) {
            uint4 raw[8];
            float wt[8];
            #pragma unroll
            for (int pp = 0; pp < 2; ++pp) {
                const int j = h * 12 + rep * 6 + g * 2 + pp;
                const int4   ix = *reinterpret_cast<const int4*>(&s_idx[j * 4]);
                const float4 tw = *reinterpret_cast<const float4*>(&s_twt[j * 4]);
                raw[pp * 4 + 0] = *reinterpret_cast<const uint4*>(vb + ix.x);
                raw[pp * 4 + 1] = *reinterpret_cast<const uint4*>(vb + ix.y);
                raw[pp * 4 + 2] = *reinterpret_cast<const uint4*>(vb + ix.z);
                raw[pp * 4 + 3] = *reinterpret_cast<const uint4*>(vb + ix.w);
                wt[pp * 4 + 0] = tw.x; wt[pp * 4 + 1] = tw.y;
                wt[pp * 4 + 2] = tw.z; wt[pp * 4 + 3] = tw.w;
            }
            #pragma unroll
            for (int k = 0; k < 8; ++k) {
                acc[0] += wt[k] * __uint_as_float(raw[k].x << 16);
                acc[1] += wt[k] * __uint_as_float(raw[k].x & 0xffff0000u);
                acc[2] += wt[k] * __uint_as_float(raw[k].y << 16);
                acc[3] += wt[k] * __uint_as_float(raw[k].y & 0xffff0000u);
                acc[4] += wt[k] * __uint_as_float(raw[k].z << 16);
                acc[5] += wt[k] * __uint_as_float(raw[k].z & 0xffff0000u);
                acc[6] += wt[k] * __uint_as_float(raw[k].w << 16);
                acc[7] += wt[k] * __uint_as_float(raw[k].w & 0xffff0000u);
            }
        }

        const float inv = s_inv[h];
        #pragma unroll
        for (int c = 0; c < 8; ++c)
            acc[c] = (acc[c] + __shfl_xor(acc[c], 4)) * inv;

        if (rep == 0) {
            uint4 o;
            o.x = (u32)bf_of(acc[0]) | ((u32)bf_of(acc[1]) << 16);
            o.y = (u32)bf_of(acc[2]) | ((u32)bf_of(acc[3]) << 16);
            o.z = (u32)bf_of(acc[4]) | ((u32)bf_of(acc[5]) << 16);
            o.w = (u32)bf_of(acc[6]) | ((u32)bf_of(acc[7]) << 16);
            *reinterpret_cast<uint4*>(&t_lds[r * TSTR + h * HD + oct * 8]) = o;
        }
    }

    __syncthreads();   // t_lds complete

    // ---------------- phase B: out = t_lds @ Wo^T + bo ----------------
    // wave w covers cols w*32..w*32+31 (ni 0..1); rows 0..15 (one frag row).
    const int qm   = lane & 15;
    const int quad = lane >> 4;

    f32x4 acc2[2];
    acc2[0] = (f32x4){0.f, 0.f, 0.f, 0.f};
    acc2[1] = (f32x4){0.f, 0.f, 0.f, 0.f};

    #pragma unroll
    for (int k0 = 0; k0 < CDIM; k0 += 32) {
        const bf16x8 fa = *reinterpret_cast<const bf16x8*>(
            &t_lds[qm * TSTR + k0 + quad * 8]);
        #pragma unroll
        for (int ni = 0; ni < 2; ++ni) {
            const int rn = wave * 32 + ni * 16 + qm;
            const bf16x8 fb = *reinterpret_cast<const bf16x8*>(
                &wo_h[(size_t)rn * CDIM + k0 + quad * 8]);
            acc2[ni] = __builtin_amdgcn_mfma_f32_16x16x32_bf16(
                fa, fb, acc2[ni], 0, 0, 0);
        }
    }

    #pragma unroll
    for (int ni = 0; ni < 2; ++ni) {
        const int n  = wave * 32 + ni * 16 + qm;
        const float bn = bo[n];
        #pragma unroll
        for (int r = 0; r < 4; ++r) {
            const int m = bq0 + quad * 4 + r;
            out[(size_t)m * CDIM + n] = acc2[ni][r] + bn;
        }
    }
}

// ---------------------------------------------------------------------------
// Launch: 2 dispatches.
// ---------------------------------------------------------------------------
extern "C" void kernel_launch(void* const* d_in, const int* in_sizes, int n_in,
                              void* d_out, int out_size, void* d_ws, size_t ws_size,
                              hipStream_t stream)
{
    const float* query = (const float*)d_in[0];   // (B,NQ,C)
    const float* refp  = (const float*)d_in[1];   // (B,NQ,2)
    const float* value = (const float*)d_in[2];   // (B,NV,C)
    const float* Wv    = (const float*)d_in[3];   // (C,C)
    const float* bv    = (const float*)d_in[4];
    const float* Woff  = (const float*)d_in[5];   // (192,C)
    const float* boff  = (const float*)d_in[6];
    const float* Wa    = (const float*)d_in[7];   // (96,C)
    const float* ba    = (const float*)d_in[8];
    const float* Wo    = (const float*)d_in[9];   // (C,C)
    const float* bo    = (const float*)d_in[10];
    float* out = (float*)d_out;

    // ---- workspace layout (all bf16) ----
    char* w = (char*)d_ws;
    const size_t SZ_T = (size_t)MROWS * CDIM * 2;     // 5.5 MB
    u16* v_bf16 = (u16*)(w);                          // head-major gather source
    u16* ws_off = (u16*)(w + 1 * SZ_T);               // (MROWS,192) bf16
    u16* ws_a   = (u16*)(w + 1 * SZ_T + (size_t)MROWS * NOFF * 2);
    u16* wo_h   = (u16*)(w + 1 * SZ_T + (size_t)MROWS * NQA * 2);  // (256,256)

    const dim3 blk(256);

    // 1) v-GEMM + qa-GEMM with inline conversion (+ Wo->bf16 side-job)
    gemm_vqa_conv<<<dim3(K1_BLOCKS), blk, 0, stream>>>(
        value, Wv, bv, v_bf16,
        query, Woff, Wa, boff, ba, ws_off, ws_a,
        Wo, wo_h);

    // 2) msda + out-GEMM fused (t stays in LDS)
    msda_out_kernel<<<dim3(K2_BLOCKS), dim3(512), 0, stream>>>(
        ws_off, ws_a, refp, v_bf16, wo_h, bo, out);
}